// Round 7
// baseline (1771.854 us; speedup 1.0000x reference)
//
#include <hip/hip_runtime.h>
#include <cstdint>
#include <cstddef>

// ---------------------------------------------------------------------------
// PointConv Set Abstraction forward, MI355X (gfx950).
// B=8, N=4096, D=61, S=1024, K=32; MLP 64->64->64->128 ; WeightNet 3->8->8->16
// Output: concat( new_xyz [B,3,S], out [B,128,S] ) fp32.
// R7 == R6 resubmitted (R6 bench failed on GPU acquisition; kernel never ran).
// R6: fps restructured around the R5 post-mortem finding that per-iter cost
//     (~1600cy) is invariant to reduction style => dominated by 8-wave
//     barrier + two serial LDS round-trips. Now: 4 waves x 16 pts, two-phase
//     f32-max/u32-min DPP reduce, and slots carry candidate COORDS (owner
//     lane writes them pre-barrier) so the post-barrier winner-coord fetch is
//     one overlapped LDS round (no dependent pts4[winner] read).
//     Rest of pipeline identical to R5 (passed).
// ---------------------------------------------------------------------------

constexpr int B_ = 8, N_ = 4096, D_ = 61, S_ = 1024, K_ = 32;
constexpr int P_ = B_ * S_ * K_;          // 262144 positions (b,s,k)
constexpr int BS_ = B_ * S_;              // 8192

// ---------------- workspace layout (bytes) ----------------
constexpr size_t OFF_STATS  = 0;                          // 8192 B, zeroed
constexpr size_t OFF_NEWXYZ = 8192;                       // [B*S][3] f32
constexpr size_t OFF_KNN    = 106496;                     // [P] int
constexpr size_t OFF_PT     = 1155072;                    // [B*N][64] f32 padded
constexpr size_t OFF_Y01    = 9543680;                    // [64][P] f32 (also aggbuf alias)
constexpr size_t OFF_Y2     = 76652544;                   // [128][P] f32
constexpr size_t OFF_W01    = 210870272;                  // [8][P] f32 (outpre alias after dead)
constexpr size_t OFF_W2B    = 219258880;                  // [16][P] f32
constexpr size_t OFF_OUTPRE = OFF_W01;                    // [8192][128] f32 (w01 dead by lin)

// ---------------- host threefry (JAX PRNG reproduction) ----------------
static inline uint32_t rotl32(uint32_t x, int r){ return (x << r) | (x >> (32 - r)); }
static void tf2x32(uint32_t k0, uint32_t k1, uint32_t x0, uint32_t x1,
                   uint32_t* o0, uint32_t* o1){
  uint32_t ks[3] = {k0, k1, k0 ^ k1 ^ 0x1BD11BDAu};
  x0 += ks[0]; x1 += ks[1];
  const int RA[4] = {13,15,26,6}, RB[4] = {17,29,16,24};
  for (int i = 0; i < 5; ++i){
    const int* R = (i & 1) ? RB : RA;
    for (int j = 0; j < 4; ++j){ x0 += x1; x1 = rotl32(x1, R[j]); x1 ^= x0; }
    x0 += ks[(i+1)%3]; x1 += ks[(i+2)%3] + (uint32_t)(i+1);
  }
  *o0 = x0; *o1 = x1;
}
struct StartIdx { int v[8]; };
static StartIdx compute_starts(){
  uint32_t ka, kb;
  tf2x32(0u, 42u, 0u, 1u, &ka, &kb);          // split(key)[1]
  StartIdx s;
  for (int i = 0; i < 8; ++i){
    uint32_t b1, b2;
    tf2x32(ka, kb, 0u, (uint32_t)i, &b1, &b2);
    s.v[i] = (int)((b1 ^ b2) & 4095u);        // MODE 1 (validated in R1)
  }
  return s;
}

// ---------------- DPP helpers (wave64) ----------------
template<int C>
__device__ __forceinline__ float dpp_max_f32_step(float x){
  // identity 0 valid: operands >= 0
  int t = __builtin_amdgcn_update_dpp(0, (int)__float_as_uint(x), C, 0xf, 0xf, true);
  return fmaxf(x, __uint_as_float((unsigned)t));
}
__device__ __forceinline__ float dpp_wave_max_f32(float x){
  x = dpp_max_f32_step<0x111>(x);
  x = dpp_max_f32_step<0x112>(x);
  x = dpp_max_f32_step<0x114>(x);
  x = dpp_max_f32_step<0x118>(x);
  x = dpp_max_f32_step<0x142>(x);
  x = dpp_max_f32_step<0x143>(x);
  return __uint_as_float((unsigned)__builtin_amdgcn_readlane((int)__float_as_uint(x), 63));
}
template<int C>
__device__ __forceinline__ unsigned dpp_min_u32_step(unsigned x){
  int t = __builtin_amdgcn_update_dpp(-1, (int)x, C, 0xf, 0xf, false); // identity ~0
  unsigned u = (unsigned)t;
  return u < x ? u : x;
}
__device__ __forceinline__ unsigned dpp_wave_min_u32(unsigned x){
  x = dpp_min_u32_step<0x111>(x);
  x = dpp_min_u32_step<0x112>(x);
  x = dpp_min_u32_step<0x114>(x);
  x = dpp_min_u32_step<0x118>(x);
  x = dpp_min_u32_step<0x142>(x);
  x = dpp_min_u32_step<0x143>(x);
  return (unsigned)__builtin_amdgcn_readlane((int)x, 63);
}
template<int C>
__device__ __forceinline__ unsigned long long dpp_min_u64_step(unsigned long long k){
  unsigned lo = (unsigned)k, hi = (unsigned)(k >> 32);
  unsigned olo = (unsigned)__builtin_amdgcn_update_dpp(-1, (int)lo, C, 0xf, 0xf, false);
  unsigned ohi = (unsigned)__builtin_amdgcn_update_dpp(-1, (int)hi, C, 0xf, 0xf, false);
  unsigned long long o = ((unsigned long long)ohi << 32) | olo;
  return o < k ? o : k;
}
__device__ __forceinline__ unsigned long long dpp_wave_min_u64(unsigned long long k){
  k = dpp_min_u64_step<0x111>(k);
  k = dpp_min_u64_step<0x112>(k);
  k = dpp_min_u64_step<0x114>(k);
  k = dpp_min_u64_step<0x118>(k);
  k = dpp_min_u64_step<0x142>(k);
  k = dpp_min_u64_step<0x143>(k);
  unsigned lo = (unsigned)__builtin_amdgcn_readlane((int)(unsigned)k, 63);
  unsigned hi = (unsigned)__builtin_amdgcn_readlane((int)(unsigned)(k >> 32), 63);
  return ((unsigned long long)hi << 32) | lo;
}
template<int C>
__device__ __forceinline__ float dpp_add_step(float x){
  int t = __builtin_amdgcn_update_dpp(0, (int)__float_as_uint(x), C, 0xf, 0xf, true);
  return x + __uint_as_float((unsigned)t);
}
__device__ __forceinline__ float dpp_row_sum16(float x){
  x = dpp_add_step<0x111>(x);
  x = dpp_add_step<0x112>(x);
  x = dpp_add_step<0x114>(x);
  x = dpp_add_step<0x118>(x);
  return x;
}
__device__ __forceinline__ unsigned ordf(float f){
  unsigned u = __float_as_uint(f);
  return u ^ (unsigned)(((int)u >> 31) | 0x80000000);
}
__device__ __forceinline__ void atomAddD(double* p, double v){
  __hip_atomic_fetch_add(p, v, __ATOMIC_RELAXED, __HIP_MEMORY_SCOPE_AGENT);
}

// ---------------- fused FPS (blocks 0..7) + transpose (blocks 8..519) ------
#define REP16(M) M(0) M(1) M(2) M(3) M(4) M(5) M(6) M(7) \
                 M(8) M(9) M(10) M(11) M(12) M(13) M(14) M(15)

__global__ __launch_bounds__(256, 1) void fps_tr_kernel(const float* __restrict__ xyz,
                                                        const float* __restrict__ pts,
                                                        StartIdx st,
                                                        float* __restrict__ new_xyz,
                                                        float* __restrict__ out_xyz,
                                                        float* __restrict__ pT){
  __shared__ float4 pts4[N_];                     // 64 KiB (tr: aliased tile)
  __shared__ unsigned short win[S_];              // 2 KiB winner ring
  __shared__ unsigned long long slotK[2][4];
  __shared__ float4 slotC[2][4];
  const int tid = threadIdx.x;

  if (blockIdx.x >= 8){
    // ---- transpose tile: [B,61,N] -> [B][N][64] padded ----
    float* tile = (float*)pts4;                   // [61][65]
    const int tt = blockIdx.x - 8;
    const int b = tt >> 6, n0 = (tt & 63) * 64;
    for (int e = tid; e < 61*64; e += 256){
      int d = e >> 6, c = e & 63;
      tile[d*65 + c] = pts[((size_t)b*61 + d)*N_ + n0 + c];
    }
    __syncthreads();
    for (int e = tid; e < 4096; e += 256){
      int r = e >> 6, d = e & 63;
      pT[((size_t)b*N_ + n0 + r)*64 + d] = (d < 61) ? tile[d*65 + r] : 0.f;
    }
    return;
  }

  // ---- FPS: exact reproduction of reference scan ----
  const int b = blockIdx.x;
  const int lane = tid & 63, wv = tid >> 6;       // 4 waves
  const float* xb = xyz + (size_t)b*3*N_;

#define LOADP(i) \
  float px##i = xb[tid + 256*(i)]; \
  float py##i = xb[N_ + tid + 256*(i)]; \
  float pz##i = xb[2*N_ + tid + 256*(i)]; \
  float dm##i = 1e10f; \
  pts4[tid + 256*(i)] = make_float4(px##i, py##i, pz##i, 0.f);
  REP16(LOADP)
#undef LOADP
  __syncthreads();

  int cur = st.v[b];
  float4 c4 = pts4[cur];
  float cx = c4.x, cy = c4.y, cz = c4.z;

  int par = 0;
  for (int s = 0; s < S_; ++s){
    if (tid == 0) win[s] = (unsigned short)cur;
    // distance + dmin update (exact reference float semantics: rn ops, no FMA)
#define UPD(i) { \
      float dx = __fsub_rn(px##i, cx), dy = __fsub_rn(py##i, cy), dz = __fsub_rn(pz##i, cz); \
      float d  = __fadd_rn(__fadd_rn(__fmul_rn(dx,dx), __fmul_rn(dy,dy)), __fmul_rn(dz,dz)); \
      dm##i = fminf(dm##i, d); }
    REP16(UPD)
#undef UPD
    // phase A: block-local wave max of dmin (f32 tree + DPP)
    float a0 = fmaxf(dm0, dm1),  a1 = fmaxf(dm2, dm3);
    float a2 = fmaxf(dm4, dm5),  a3 = fmaxf(dm6, dm7);
    float a4 = fmaxf(dm8, dm9),  a5 = fmaxf(dm10, dm11);
    float a6 = fmaxf(dm12, dm13),a7 = fmaxf(dm14, dm15);
    float b0 = fmaxf(a0, a1), b1 = fmaxf(a2, a3), b2 = fmaxf(a4, a5), b3 = fmaxf(a6, a7);
    float lmax = fmaxf(fmaxf(b0, b1), fmaxf(b2, b3));
    const float wmax = dpp_wave_max_f32(lmax);
    // phase B: wave min index among dm == wmax (idx = tid | (i<<8))
#define CANDI(i) unsigned c##i = (dm##i == wmax) ? (unsigned)(tid | ((i) << 8)) : 0xFFFFFFFFu;
    REP16(CANDI)
#undef CANDI
    unsigned d0 = c0  < c1  ? c0  : c1,  d1 = c2  < c3  ? c2  : c3;
    unsigned d2 = c4  < c5  ? c4  : c5,  d3 = c6  < c7  ? c6  : c7;
    unsigned d4 = c8  < c9  ? c8  : c9,  d5 = c10 < c11 ? c10 : c11;
    unsigned d6 = c12 < c13 ? c12 : c13, d7 = c14 < c15 ? c14 : c15;
    unsigned e0 = d0 < d1 ? d0 : d1, e1 = d2 < d3 ? d2 : d3;
    unsigned e2 = d4 < d5 ? d4 : d5, e3 = d6 < d7 ? d6 : d7;
    unsigned f0 = e0 < e1 ? e0 : e1, f1 = e2 < e3 ? e2 : e3;
    unsigned cand = f0 < f1 ? f0 : f1;
    const unsigned widx = dpp_wave_min_u32(cand);   // wave winner (global idx)
    // owner lane publishes key + coords for its wave (masked select, pre-barrier)
    if (tid == (int)(widx & 255u)){
      const int sl = (int)(widx >> 8);
      float sx = px0, sy = py0, sz = pz0;
#define SEL(i) if (sl == (i)){ sx = px##i; sy = py##i; sz = pz##i; }
      SEL(1) SEL(2) SEL(3) SEL(4) SEL(5) SEL(6) SEL(7) SEL(8)
      SEL(9) SEL(10) SEL(11) SEL(12) SEL(13) SEL(14) SEL(15)
#undef SEL
      slotK[par][wv] = ((unsigned long long)__float_as_uint(wmax) << 32)
                     | (unsigned long long)(unsigned)(~widx);
      slotC[par][wv] = make_float4(sx, sy, sz, 0.f);
    }
    __syncthreads();
    // one overlapped LDS round: 4 keys + 4 coord vectors
    unsigned long long k0 = slotK[par][0], k1 = slotK[par][1],
                       k2 = slotK[par][2], k3 = slotK[par][3];
    float4 q0 = slotC[par][0], q1 = slotC[par][1],
           q2 = slotC[par][2], q3 = slotC[par][3];
    unsigned long long m0 = k0; float4 g0 = q0;
    if (k1 > m0){ m0 = k1; g0 = q1; }
    unsigned long long m1 = k2; float4 g1 = q2;
    if (k3 > m1){ m1 = k3; g1 = q3; }
    if (m1 > m0){ m0 = m1; g0 = g1; }
    cur = (int)(~(unsigned)m0) & (N_ - 1);
    cx = g0.x; cy = g0.y; cz = g0.z;
    par ^= 1;
  }
  __syncthreads();
  // epilogue: all output writes at once
  for (int s2 = tid; s2 < S_; s2 += 256){
    float4 p = pts4[win[s2]];
    new_xyz[((size_t)b*S_ + s2)*3 + 0] = p.x;
    new_xyz[((size_t)b*S_ + s2)*3 + 1] = p.y;
    new_xyz[((size_t)b*S_ + s2)*3 + 2] = p.z;
    out_xyz[(size_t)b*3*S_ + s2]        = p.x;
    out_xyz[(size_t)b*3*S_ + S_ + s2]   = p.y;
    out_xyz[(size_t)b*3*S_ + 2*S_ + s2] = p.z;
  }
}
#undef REP16

// ---------------- KNN: 32 smallest sqdist per query, wave per query --------
__global__ __launch_bounds__(256) void knn_kernel(const float* __restrict__ xyz,
                                                  const float* __restrict__ nxyz,
                                                  int* __restrict__ knn_idx){
  __shared__ float dist[4][4096];           // 64 KiB
  const int wv = threadIdx.x >> 6, lane = threadIdx.x & 63;
  const int q = blockIdx.x*4 + wv;          // 0..8191
  const int b = q >> 10;
  const float* xb = xyz + (size_t)b*3*N_;
  const float ax = nxyz[(size_t)q*3], ay = nxyz[(size_t)q*3+1], az = nxyz[(size_t)q*3+2];
  const float sa = __fadd_rn(__fadd_rn(__fmul_rn(ax,ax), __fmul_rn(ay,ay)), __fmul_rn(az,az));
  float* dw = dist[wv];
  unsigned long long kk = ~0ull;
  for (int i = 0; i < 64; ++i){
    int n = i*64 + lane;
    float x = xb[n], y = xb[N_+n], z = xb[2*N_+n];
    float sb  = __fadd_rn(__fadd_rn(__fmul_rn(x,x), __fmul_rn(y,y)), __fmul_rn(z,z));
    float dot = __fadd_rn(__fadd_rn(__fmul_rn(ax,x), __fmul_rn(ay,y)), __fmul_rn(az,z));
    float d   = __fsub_rn(__fadd_rn(sa, sb), __fmul_rn(2.f, dot));
    dw[i*64 + ((lane + i) & 63)] = d;       // swizzled store
    unsigned long long key = ((unsigned long long)ordf(d) << 32) | (unsigned)n;
    if (key < kk) kk = key;
  }
  __syncthreads();
  int myout = 0;
  for (int r = 0; r < 32; ++r){
    unsigned long long g = dpp_wave_min_u64(kk);
    const int gn = (int)(g & 0xFFFFFFFFull);
    if (lane == r) myout = gn;
    const int col = gn & 63, row = gn >> 6;
    const int a = lane*64 + ((col + lane) & 63);
    float v = dw[a];
    if (lane == row){ v = 3.4e38f; dw[a] = 3.4e38f; }
    unsigned long long nk = ((unsigned long long)ordf(v) << 32)
                          | (unsigned)(lane*64 + col);
    nk = dpp_wave_min_u64(nk);
    if (lane == col) kk = nk;
  }
  if (lane < 32) knn_idx[(size_t)q*32 + lane] = myout;
}

// helper: BN scale/shift from stats
__device__ __forceinline__ void bn_coeff(const double* st, const float* g, const float* be,
                                         int c, double cnt, float* sc, float* sh){
  double mean = st[c*2] / cnt;
  double var  = st[c*2+1] / cnt - mean*mean;
  double scale = (double)g[c] / sqrt(var + 1e-5);
  *sc = (float)scale; *sh = (float)((double)be[c] - mean*scale);
}

// fused 64-channel stats epilogue (256-thread block)
#define STATS64(ACC_EXPR, ST, CH_OFF)                                          \
  {                                                                            \
    _Pragma("unroll")                                                          \
    for (int o = 0; o < 64; ++o){                                              \
      float v_ = (ACC_EXPR);                                                   \
      float s1_ = dpp_row_sum16(v_);                                           \
      float q1_ = dpp_row_sum16(v_*v_);                                        \
      if ((threadIdx.x & 15) == 15){                                           \
        int rid_ = threadIdx.x >> 4;                                           \
        redS[rid_][o] = s1_; redQ[rid_][o] = q1_;                              \
      }                                                                        \
    }                                                                          \
    __syncthreads();                                                           \
    if (threadIdx.x < 64){                                                     \
      float s_ = 0.f;                                                          \
      _Pragma("unroll")                                                        \
      for (int r_ = 0; r_ < 16; ++r_) s_ += redS[r_][threadIdx.x];             \
      atomAddD(&(ST)[((CH_OFF) + threadIdx.x)*2], (double)s_);                 \
    } else if (threadIdx.x < 128){                                             \
      int o_ = threadIdx.x - 64;                                               \
      float s_ = 0.f;                                                          \
      _Pragma("unroll")                                                        \
      for (int r_ = 0; r_ < 16; ++r_) s_ += redQ[r_][o_];                      \
      atomAddD(&(ST)[((CH_OFF) + o_)*2 + 1], (double)s_);                      \
    }                                                                          \
  }

// ---------------- MLP layer 0: gather + 64->64 + bias -> y [64][P] ---------
__global__ __launch_bounds__(256, 2) void m0_kernel(const float* __restrict__ pT,
                                                    const float* __restrict__ xyz,
                                                    const float* __restrict__ nxyz,
                                                    const int* __restrict__ knn_idx,
                                                    const float* __restrict__ w,
                                                    const float* __restrict__ bias,
                                                    float* __restrict__ y,
                                                    double* __restrict__ stout){
  __shared__ float Wt[4096]; __shared__ float bb[64];
  __shared__ float redS[16][65], redQ[16][65];
  for (int t = threadIdx.x; t < 4096; t += 256){ int o = t >> 6, c = t & 63; Wt[c*64+o] = w[o*64+c]; }
  if (threadIdx.x < 64) bb[threadIdx.x] = bias[threadIdx.x];
  __syncthreads();
  const int p = blockIdx.x*256 + threadIdx.x;
  const int b = p >> 15, s = (p & 32767) >> 5;
  const int n = knn_idx[p];
  float in[64];
  {
    const float* xb = xyz + (size_t)b*3*N_;
    const int q = (b << 10) + s;
    in[0] = xb[n]       - nxyz[(size_t)q*3];
    in[1] = xb[N_+n]    - nxyz[(size_t)q*3+1];
    in[2] = xb[2*N_+n]  - nxyz[(size_t)q*3+2];
    const float* pr = pT + ((size_t)b*N_ + n)*64;
#pragma unroll
    for (int d = 0; d < 60; d += 4){
      float4 v = *reinterpret_cast<const float4*>(&pr[d]);
      in[3+d] = v.x; in[4+d] = v.y; in[5+d] = v.z; in[6+d] = v.w;
    }
    in[63] = pr[60];
  }
  float acc[64];
#pragma unroll
  for (int o = 0; o < 64; ++o) acc[o] = bb[o];
#pragma unroll
  for (int c = 0; c < 64; ++c){
    float x = in[c];
#pragma unroll
    for (int o = 0; o < 64; o += 4){
      float4 w4 = *reinterpret_cast<const float4*>(&Wt[c*64+o]);
      acc[o]   += x*w4.x; acc[o+1] += x*w4.y; acc[o+2] += x*w4.z; acc[o+3] += x*w4.w;
    }
  }
#pragma unroll
  for (int o = 0; o < 64; ++o) y[(size_t)o*P_ + p] = acc[o];
  STATS64(acc[o], stout, 0)
}

// ---------------- MLP layer 1: bn(relu) then 64->64, in place --------------
__global__ __launch_bounds__(256, 2) void m1_kernel(float* __restrict__ y,
                                                    const float* __restrict__ w,
                                                    const float* __restrict__ bias,
                                                    const double* __restrict__ stin,
                                                    const float* __restrict__ g,
                                                    const float* __restrict__ be,
                                                    double* __restrict__ stout){
  __shared__ float Wt[4096]; __shared__ float bb[64], sc[64], sh[64];
  __shared__ float redS[16][65], redQ[16][65];
  for (int t = threadIdx.x; t < 4096; t += 256){ int o = t >> 6, c = t & 63; Wt[c*64+o] = w[o*64+c]; }
  if (threadIdx.x < 64){
    bn_coeff(stin, g, be, threadIdx.x, (double)P_, &sc[threadIdx.x], &sh[threadIdx.x]);
    bb[threadIdx.x] = bias[threadIdx.x];
  }
  __syncthreads();
  const int p = blockIdx.x*256 + threadIdx.x;
  float in[64];
#pragma unroll
  for (int c = 0; c < 64; ++c){
    float x = y[(size_t)c*P_ + p];
    in[c] = fmaxf(0.f, fmaf(x, sc[c], sh[c]));
  }
  float acc[64];
#pragma unroll
  for (int o = 0; o < 64; ++o) acc[o] = bb[o];
#pragma unroll
  for (int c = 0; c < 64; ++c){
    float x = in[c];
#pragma unroll
    for (int o = 0; o < 64; o += 4){
      float4 w4 = *reinterpret_cast<const float4*>(&Wt[c*64+o]);
      acc[o]   += x*w4.x; acc[o+1] += x*w4.y; acc[o+2] += x*w4.z; acc[o+3] += x*w4.w;
    }
  }
#pragma unroll
  for (int o = 0; o < 64; ++o) y[(size_t)o*P_ + p] = acc[o];
  STATS64(acc[o], stout, 0)
}

// ---------------- MLP layer 2: bn(relu) then 64->128 (half per blockIdx.y) -
__global__ __launch_bounds__(256, 2) void m2_kernel(const float* __restrict__ y1,
                                                    float* __restrict__ y2,
                                                    const float* __restrict__ w,
                                                    const float* __restrict__ bias,
                                                    const double* __restrict__ stin,
                                                    const float* __restrict__ g,
                                                    const float* __restrict__ be,
                                                    double* __restrict__ stout){
  __shared__ float Wt[4096]; __shared__ float bb[64], sc[64], sh[64];
  __shared__ float redS[16][65], redQ[16][65];
  const int half = blockIdx.y;
  for (int t = threadIdx.x; t < 4096; t += 256){
    int o = t >> 6, c = t & 63;
    Wt[c*64+o] = w[(size_t)(half*64+o)*64 + c];
  }
  if (threadIdx.x < 64){
    bn_coeff(stin, g, be, threadIdx.x, (double)P_, &sc[threadIdx.x], &sh[threadIdx.x]);
    bb[threadIdx.x] = bias[half*64 + threadIdx.x];
  }
  __syncthreads();
  const int p = blockIdx.x*256 + threadIdx.x;
  float in[64];
#pragma unroll
  for (int c = 0; c < 64; ++c){
    float x = y1[(size_t)c*P_ + p];
    in[c] = fmaxf(0.f, fmaf(x, sc[c], sh[c]));
  }
  float acc[64];
#pragma unroll
  for (int o = 0; o < 64; ++o) acc[o] = bb[o];
#pragma unroll
  for (int c = 0; c < 64; ++c){
    float x = in[c];
#pragma unroll
    for (int o = 0; o < 64; o += 4){
      float4 w4 = *reinterpret_cast<const float4*>(&Wt[c*64+o]);
      acc[o]   += x*w4.x; acc[o+1] += x*w4.y; acc[o+2] += x*w4.z; acc[o+3] += x*w4.w;
    }
  }
#pragma unroll
  for (int o = 0; o < 64; ++o) y2[(size_t)(half*64+o)*P_ + p] = acc[o];
  STATS64(acc[o], stout, half*64)
}

// ---------------- WeightNet layer 0: gather g_norm, 3->8 + stats -----------
__global__ __launch_bounds__(256) void w0_kernel(const float* __restrict__ xyz,
                                                 const float* __restrict__ nxyz,
                                                 const int* __restrict__ knn_idx,
                                                 const float* __restrict__ w,   // [8][3]
                                                 const float* __restrict__ bias,
                                                 float* __restrict__ wb,
                                                 double* __restrict__ stout){
  __shared__ float Wl[24], bb[8];
  __shared__ float redS[16][9], redQ[16][9];
  if (threadIdx.x < 24) Wl[threadIdx.x] = w[threadIdx.x];
  if (threadIdx.x < 8)  bb[threadIdx.x] = bias[threadIdx.x];
  __syncthreads();
  const int p = blockIdx.x*256 + threadIdx.x;
  const int b = p >> 15, s = (p & 32767) >> 5;
  const int n = knn_idx[p];
  const float* xb = xyz + (size_t)b*3*N_;
  const int q = (b << 10) + s;
  float gx = xb[n]      - nxyz[(size_t)q*3];
  float gy = xb[N_+n]   - nxyz[(size_t)q*3+1];
  float gz = xb[2*N_+n] - nxyz[(size_t)q*3+2];
  float a_[8];
#pragma unroll
  for (int o = 0; o < 8; ++o){
    a_[o] = bb[o] + gx*Wl[o*3] + gy*Wl[o*3+1] + gz*Wl[o*3+2];
    wb[(size_t)o*P_ + p] = a_[o];
  }
#pragma unroll
  for (int o = 0; o < 8; ++o){
    float s1 = dpp_row_sum16(a_[o]);
    float q1 = dpp_row_sum16(a_[o]*a_[o]);
    if ((threadIdx.x & 15) == 15){ int rid = threadIdx.x >> 4; redS[rid][o] = s1; redQ[rid][o] = q1; }
  }
  __syncthreads();
  if (threadIdx.x < 8){
    float s_ = 0.f;
#pragma unroll
    for (int r = 0; r < 16; ++r) s_ += redS[r][threadIdx.x];
    atomAddD(&stout[threadIdx.x*2], (double)s_);
  } else if (threadIdx.x < 16){
    int o = threadIdx.x - 8;
    float s_ = 0.f;
#pragma unroll
    for (int r = 0; r < 16; ++r) s_ += redQ[r][o];
    atomAddD(&stout[o*2+1], (double)s_);
  }
}

// ---------------- WeightNet layer 1: bn relu 8->8 in place + stats ---------
__global__ __launch_bounds__(256) void w1_kernel(float* __restrict__ wb,
                                                 const float* __restrict__ w,   // [8][8]
                                                 const float* __restrict__ bias,
                                                 const double* __restrict__ stin,
                                                 const float* __restrict__ g,
                                                 const float* __restrict__ be,
                                                 double* __restrict__ stout){
  __shared__ float Wl[64], bb[8], sc[8], sh[8];
  __shared__ float redS[16][9], redQ[16][9];
  if (threadIdx.x < 64) Wl[threadIdx.x] = w[threadIdx.x];
  if (threadIdx.x < 8){
    bn_coeff(stin, g, be, threadIdx.x, (double)P_, &sc[threadIdx.x], &sh[threadIdx.x]);
    bb[threadIdx.x] = bias[threadIdx.x];
  }
  __syncthreads();
  const int p = blockIdx.x*256 + threadIdx.x;
  float in[8];
#pragma unroll
  for (int c = 0; c < 8; ++c){
    float x = wb[(size_t)c*P_ + p];
    in[c] = fmaxf(0.f, fmaf(x, sc[c], sh[c]));
  }
  float acc[8];
#pragma unroll
  for (int o = 0; o < 8; ++o){
    float a = bb[o];
#pragma unroll
    for (int c = 0; c < 8; ++c) a += in[c]*Wl[o*8+c];
    acc[o] = a;
  }
#pragma unroll
  for (int o = 0; o < 8; ++o) wb[(size_t)o*P_ + p] = acc[o];
#pragma unroll
  for (int o = 0; o < 8; ++o){
    float s1 = dpp_row_sum16(acc[o]);
    float q1 = dpp_row_sum16(acc[o]*acc[o]);
    if ((threadIdx.x & 15) == 15){ int rid = threadIdx.x >> 4; redS[rid][o] = s1; redQ[rid][o] = q1; }
  }
  __syncthreads();
  if (threadIdx.x < 8){
    float s_ = 0.f;
#pragma unroll
    for (int r = 0; r < 16; ++r) s_ += redS[r][threadIdx.x];
    atomAddD(&stout[threadIdx.x*2], (double)s_);
  } else if (threadIdx.x < 16){
    int o = threadIdx.x - 8;
    float s_ = 0.f;
#pragma unroll
    for (int r = 0; r < 16; ++r) s_ += redQ[r][o];
    atomAddD(&stout[o*2+1], (double)s_);
  }
}

// ---------------- WeightNet layer 2: bn relu 8->16 + stats -----------------
__global__ __launch_bounds__(256) void w2_kernel(const float* __restrict__ wb,
                                                 float* __restrict__ wb2,
                                                 const float* __restrict__ w,   // [16][8]
                                                 const float* __restrict__ bias,
                                                 const double* __restrict__ stin,
                                                 const float* __restrict__ g,
                                                 const float* __restrict__ be,
                                                 double* __restrict__ stout){
  __shared__ float Wl[128], bb[16], sc[8], sh[8];
  __shared__ float redS[16][17], redQ[16][17];
  if (threadIdx.x < 128) Wl[threadIdx.x] = w[threadIdx.x];
  if (threadIdx.x < 8)
    bn_coeff(stin, g, be, threadIdx.x, (double)P_, &sc[threadIdx.x], &sh[threadIdx.x]);
  if (threadIdx.x < 16) bb[threadIdx.x] = bias[threadIdx.x];
  __syncthreads();
  const int p = blockIdx.x*256 + threadIdx.x;
  float in[8];
#pragma unroll
  for (int c = 0; c < 8; ++c){
    float x = wb[(size_t)c*P_ + p];
    in[c] = fmaxf(0.f, fmaf(x, sc[c], sh[c]));
  }
  float acc[16];
#pragma unroll
  for (int o = 0; o < 16; ++o){
    float a = bb[o];
#pragma unroll
    for (int c = 0; c < 8; ++c) a += in[c]*Wl[o*8+c];
    acc[o] = a;
    wb2[(size_t)o*P_ + p] = a;
  }
#pragma unroll
  for (int o = 0; o < 16; ++o){
    float s1 = dpp_row_sum16(acc[o]);
    float q1 = dpp_row_sum16(acc[o]*acc[o]);
    if ((threadIdx.x & 15) == 15){ int rid = threadIdx.x >> 4; redS[rid][o] = s1; redQ[rid][o] = q1; }
  }
  __syncthreads();
  if (threadIdx.x < 16){
    float s_ = 0.f;
#pragma unroll
    for (int r = 0; r < 16; ++r) s_ += redS[r][threadIdx.x];
    atomAddD(&stout[threadIdx.x*2], (double)s_);
  } else if (threadIdx.x < 32){
    int o = threadIdx.x - 16;
    float s_ = 0.f;
#pragma unroll
    for (int r = 0; r < 16; ++r) s_ += redQ[r][o];
    atomAddD(&stout[o*2+1], (double)s_);
  }
}

// ---------------- agg: per (b,s) [128,K]x[K,16] -> agg row [2048] ----------
__global__ __launch_bounds__(256) void agg_kernel(const float* __restrict__ y2,
                                                  const float* __restrict__ wb2,
                                                  const double* __restrict__ st2,
                                                  const float* __restrict__ g2,
                                                  const float* __restrict__ be2,
                                                  const double* __restrict__ stw,
                                                  const float* __restrict__ gw,
                                                  const float* __restrict__ bew,
                                                  float* __restrict__ agg){
  __shared__ float f[32*132];      // [k][c] padded
  __shared__ float wt[32*16];      // [k][w]
  __shared__ float sc2[128], sh2[128], scw[16], shw[16];
  const int t = threadIdx.x;
  if (t < 128) bn_coeff(st2, g2, be2, t, (double)P_, &sc2[t], &sh2[t]);
  if (t < 16)  bn_coeff(stw, gw, bew, t, (double)P_, &scw[t], &shw[t]);
  __syncthreads();
  const int bs = blockIdx.x;
  const size_t p0 = (size_t)bs * 32;
  for (int e = t; e < 4096; e += 256){
    int c = e >> 5, k = e & 31;
    float x = y2[(size_t)c*P_ + p0 + k];
    f[k*132 + c] = fmaxf(0.f, fmaf(x, sc2[c], sh2[c]));
  }
  for (int e = t; e < 512; e += 256){
    int w = e >> 5, k = e & 31;
    float x = wb2[(size_t)w*P_ + p0 + k];
    wt[k*16 + w] = fmaxf(0.f, fmaf(x, scw[w], shw[w]));
  }
  __syncthreads();
  const int c = t >> 1, wp = (t & 1) * 8;
  float a0=0,a1=0,a2=0,a3=0,a4=0,a5=0,a6=0,a7=0;
#pragma unroll
  for (int k = 0; k < 32; ++k){
    float fv = f[k*132 + c];
    float4 u = *reinterpret_cast<const float4*>(&wt[k*16 + wp]);
    float4 v = *reinterpret_cast<const float4*>(&wt[k*16 + wp + 4]);
    a0 += fv*u.x; a1 += fv*u.y; a2 += fv*u.z; a3 += fv*u.w;
    a4 += fv*v.x; a5 += fv*v.y; a6 += fv*v.z; a7 += fv*v.w;
  }
  float* dst = agg + (size_t)bs*2048 + c*16 + wp;
  *reinterpret_cast<float4*>(dst)     = make_float4(a0,a1,a2,a3);
  *reinterpret_cast<float4*>(dst + 4) = make_float4(a4,a5,a6,a7);
}

// ---------------- linear GEMM: [8192,2048] x [128,2048]^T + b --------------
__global__ __launch_bounds__(256) void lin_kernel(const float* __restrict__ agg,
                                                  const float* __restrict__ lw,
                                                  const float* __restrict__ lb,
                                                  float* __restrict__ outp){
  __shared__ float A[32*33];        // [r][kk] padded
  __shared__ float Wl[32*128];      // [kk][o]
  __shared__ float lbs[128];
  const int t = threadIdx.x;
  const int r0 = blockIdx.x * 32;
  if (t < 128) lbs[t] = lb[t];
  const int c_lane = t & 31, rg = t >> 5;
  float acc[4][4];
#pragma unroll
  for (int i = 0; i < 4; ++i)
#pragma unroll
    for (int j = 0; j < 4; ++j) acc[i][j] = 0.f;

  for (int kk0 = 0; kk0 < 2048; kk0 += 32){
    __syncthreads();
    {
      int r = t >> 3, kq = (t & 7) * 4;
      float4 v = *reinterpret_cast<const float4*>(&agg[(size_t)(r0 + r)*2048 + kk0 + kq]);
      A[r*33 + kq]   = v.x; A[r*33 + kq+1] = v.y; A[r*33 + kq+2] = v.z; A[r*33 + kq+3] = v.w;
    }
    {
#pragma unroll
      for (int u = 0; u < 4; ++u){
        int fid = t + 256*u;
        int o = fid >> 3, kq = (fid & 7) * 4;
        float4 v = *reinterpret_cast<const float4*>(&lw[(size_t)o*2048 + kk0 + kq]);
        Wl[(kq  )*128 + o] = v.x; Wl[(kq+1)*128 + o] = v.y;
        Wl[(kq+2)*128 + o] = v.z; Wl[(kq+3)*128 + o] = v.w;
      }
    }
    __syncthreads();
#pragma unroll 8
    for (int kk = 0; kk < 32; ++kk){
      float a0 = A[(rg*4+0)*33 + kk], a1 = A[(rg*4+1)*33 + kk],
            a2 = A[(rg*4+2)*33 + kk], a3 = A[(rg*4+3)*33 + kk];
#pragma unroll
      for (int j = 0; j < 4; ++j){
        float wv = Wl[kk*128 + c_lane + 32*j];
        acc[0][j] += a0*wv; acc[1][j] += a1*wv; acc[2][j] += a2*wv; acc[3][j] += a3*wv;
      }
    }
  }
  __syncthreads();
#pragma unroll
  for (int i = 0; i < 4; ++i)
#pragma unroll
    for (int j = 0; j < 4; ++j){
      int o = c_lane + 32*j;
      outp[(size_t)(r0 + rg*4 + i)*128 + o] = acc[i][j] + lbs[o];
    }
}

// ---------------- final BN stats over (b,s) --------------------------------
__global__ __launch_bounds__(128) void statsF_kernel(const float* __restrict__ outp,
                                                     double* __restrict__ st){
  const int c = threadIdx.x;
  const int r0 = blockIdx.x * 128;
  double s = 0.0, q = 0.0;
  for (int r = 0; r < 128; ++r){
    double v = outp[(size_t)(r0 + r)*128 + c];
    s += v; q += v*v;
  }
  atomAddD(&st[c*2], s); atomAddD(&st[c*2+1], q);
}

// ---------------- final BN+relu + transpose to [B,128,S] -------------------
__global__ __launch_bounds__(256) void final_kernel(const float* __restrict__ outp,
                                                    const double* __restrict__ st,
                                                    const float* __restrict__ g,
                                                    const float* __restrict__ be,
                                                    float* __restrict__ out){
  __shared__ float sc[128], sh[128];
  __shared__ float tile[64][129];
  const int t = threadIdx.x;
  if (t < 128) bn_coeff(st, g, be, t, (double)BS_, &sc[t], &sh[t]);
  const int bs0 = blockIdx.x * 64;                 // 128 blocks
  const int b = bs0 >> 10, s0 = bs0 & 1023;
#pragma unroll
  for (int e = t; e < 8192; e += 256){
    int r = e >> 7, c = e & 127;
    tile[r][c] = outp[(size_t)(bs0 + r)*128 + c];
  }
  __syncthreads();
#pragma unroll
  for (int e = t; e < 8192; e += 256){
    int o = e >> 6, si = e & 63;
    float x = tile[si][o];
    out[(size_t)b*131072 + (size_t)o*1024 + s0 + si] = fmaxf(0.f, fmaf(x, sc[o], sh[o]));
  }
}

// ---------------------------------------------------------------------------
extern "C" void kernel_launch(void* const* d_in, const int* in_sizes, int n_in,
                              void* d_out, int out_size, void* d_ws, size_t ws_size,
                              hipStream_t stream){
  (void)in_sizes; (void)n_in; (void)out_size; (void)ws_size;
  const float* xyz    = (const float*)d_in[0];
  const float* points = (const float*)d_in[1];
  const float* mw0 = (const float*)d_in[2],  *mb0 = (const float*)d_in[3],
             * mg0 = (const float*)d_in[4],  *me0 = (const float*)d_in[5];
  const float* mw1 = (const float*)d_in[6],  *mb1 = (const float*)d_in[7],
             * mg1 = (const float*)d_in[8],  *me1 = (const float*)d_in[9];
  const float* mw2 = (const float*)d_in[10], *mb2 = (const float*)d_in[11],
             * mg2 = (const float*)d_in[12], *me2 = (const float*)d_in[13];
  const float* ww0 = (const float*)d_in[14], *wb0 = (const float*)d_in[15],
             * wg0 = (const float*)d_in[16], *we0 = (const float*)d_in[17];
  const float* ww1 = (const float*)d_in[18], *wb1 = (const float*)d_in[19],
             * wg1 = (const float*)d_in[20], *we1 = (const float*)d_in[21];
  const float* ww2 = (const float*)d_in[22], *wb2_ = (const float*)d_in[23],
             * wg2 = (const float*)d_in[24], *we2 = (const float*)d_in[25];
  const float* lw  = (const float*)d_in[26], *lb  = (const float*)d_in[27];
  const float* fg  = (const float*)d_in[28], *fb  = (const float*)d_in[29];

  char* ws = (char*)d_ws;
  double* ST0 = (double*)(ws + OFF_STATS);
  double* ST1 = (double*)(ws + OFF_STATS + 1024);
  double* ST2 = (double*)(ws + OFF_STATS + 2048);
  double* SW0 = (double*)(ws + OFF_STATS + 4096);
  double* SW1 = (double*)(ws + OFF_STATS + 4224);
  double* SW2 = (double*)(ws + OFF_STATS + 4352);
  double* STF = (double*)(ws + OFF_STATS + 4608);
  float* nxyz   = (float*)(ws + OFF_NEWXYZ);
  int*   knnidx = (int*)(ws + OFF_KNN);
  float* pT     = (float*)(ws + OFF_PT);
  float* y01    = (float*)(ws + OFF_Y01);
  float* y2     = (float*)(ws + OFF_Y2);
  float* w01    = (float*)(ws + OFF_W01);
  float* w2b    = (float*)(ws + OFF_W2B);
  float* aggbuf = (float*)(ws + OFF_Y01);   // alias: y01 dead after m2
  float* outpre = (float*)(ws + OFF_OUTPRE);// alias: w01 dead after w2

  float* out_xyz  = (float*)d_out;                      // [B,3,S]
  float* out_feat = (float*)d_out + (size_t)B_*3*S_;    // [B,128,S]

  hipMemsetAsync(ws + OFF_STATS, 0, 8192, stream);

  StartIdx st = compute_starts();
  fps_tr_kernel<<<dim3(8 + B_*64), dim3(256), 0, stream>>>(xyz, points, st, nxyz, out_xyz, pT);

  knn_kernel<<<dim3(BS_/4), dim3(256), 0, stream>>>(xyz, nxyz, knnidx);

  m0_kernel<<<dim3(P_/256), dim3(256), 0, stream>>>(pT, xyz, nxyz, knnidx, mw0, mb0, y01, ST0);
  m1_kernel<<<dim3(P_/256), dim3(256), 0, stream>>>(y01, mw1, mb1, ST0, mg0, me0, ST1);
  m2_kernel<<<dim3(P_/256, 2), dim3(256), 0, stream>>>(y01, y2, mw2, mb2, ST1, mg1, me1, ST2);

  w0_kernel<<<dim3(P_/256), dim3(256), 0, stream>>>(xyz, nxyz, knnidx, ww0, wb0, w01, SW0);
  w1_kernel<<<dim3(P_/256), dim3(256), 0, stream>>>(w01, ww1, wb1, SW0, wg0, we0, SW1);
  w2_kernel<<<dim3(P_/256), dim3(256), 0, stream>>>(w01, w2b, ww2, wb2_, SW1, wg1, we1, SW2);

  agg_kernel<<<dim3(BS_), dim3(256), 0, stream>>>(y2, w2b, ST2, mg2, me2, SW2, wg2, we2, aggbuf);
  lin_kernel<<<dim3(BS_/32), dim3(256), 0, stream>>>(aggbuf, lw, lb, outpre);
  statsF_kernel<<<dim3(BS_/128), dim3(128), 0, stream>>>(outpre, STF);
  final_kernel<<<dim3(BS_/64), dim3(256), 0, stream>>>(outpre, STF, fg, fb, out_feat);
}